// Round 13
// baseline (375.686 us; speedup 1.0000x reference)
//
#include <hip/hip_runtime.h>

#define N_NODES 50000
#define N_EDGES 800000
#define D 64

#define NPB 98                       // nodes per bucket
#define NB  511                      // buckets = ceil(50000/98) -> ~2 blocks/CU
#define CAP 1920                     // records per bucket (mean 1568, +8.9 sigma)
#define ACC_ROWS 112                 // LDS acc rows (NPB padded to 7*16)
#define BT  512                      // threads for bin (8 waves)
#define EPT 4                        // edges per thread in bin
#define CHUNK_E (BT * EPT)           // 2048 edges per block
#define NCHUNKS ((N_EDGES + CHUNK_E - 1) / CHUNK_E)   // 391
#define GT  1024                     // gather_linear threads (16 waves)

typedef unsigned short ushort_t;
typedef unsigned int   uint_t;
typedef __attribute__((ext_vector_type(8))) short   short8;
typedef __attribute__((ext_vector_type(4))) float   float4v;

// bf16 helpers (RNE down-convert; up-convert is exact)
__device__ __forceinline__ ushort_t f2b(float f) {
    uint_t u = __float_as_uint(f);
    return (ushort_t)((u + 0x7FFFu + ((u >> 16) & 1u)) >> 16);
}
__device__ __forceinline__ float b2f(ushort_t b) {
    return __uint_as_float((uint_t)b << 16);
}
__device__ __forceinline__ float lane_bcast(float v, int l) {
    return __int_as_float(__builtin_amdgcn_readlane(__float_as_int(v), l));
}

// ---------------------------------------------------------------------------
// ws layout (16B-aligned sections):
//   bedges : int2[NB*CAP]   (7.85 MB) bucket-grouped records: .x=(ld<<16)|src,
//                                      .y = fp32 weight bits
//   h_bf16 : ushort[N*D]    (6.4 MB)
//   cursor : int[NB]        (memset 0; bin rebases to b*CAP + old)
// No CSR pass, no pedges, no offs: gather accumulates per-bucket in LDS.
// ---------------------------------------------------------------------------

// ---------------- K1: bin edges by bucket (blocks < NCHUNKS) + h->bf16 (rest) ----
__global__ __launch_bounds__(BT) void bin_h2b_kernel(
    const int* __restrict__ src, const int* __restrict__ dst,
    const float* __restrict__ w, int* __restrict__ cursor,
    int2* __restrict__ bedges,
    const float* __restrict__ h, ushort_t* __restrict__ hb)
{
    if (blockIdx.x >= NCHUNKS) {
        const int nb = gridDim.x - NCHUNKS;
        for (int i = (blockIdx.x - NCHUNKS) * BT + threadIdx.x;
             i < N_NODES * D / 4; i += nb * BT) {
            const float4 v = ((const float4*)h)[i];
            ushort4 o;
            o.x = f2b(v.x); o.y = f2b(v.y); o.z = f2b(v.z); o.w = f2b(v.w);
            ((ushort4*)hb)[i] = o;
        }
        return;
    }

    __shared__ int lh[NB];
    __shared__ int loff[NB];
    __shared__ int lcur[NB];
    __shared__ int gpos[NB];
    __shared__ int part[BT];
    __shared__ int2 stage[CHUNK_E];
    __shared__ ushort_t sbk[CHUNK_E];

    const int t = threadIdx.x;
    for (int i = t; i < NB; i += BT) lh[i] = 0;
    __syncthreads();

    const int base = blockIdx.x * CHUNK_E;
    int   my_b[EPT];
    int   my_p[EPT];
    float my_w[EPT];
#pragma unroll
    for (int k = 0; k < EPT; ++k) {
        const int e = base + k * BT + t;
        if (e < N_EDGES) {
            const int d = dst[e];
            const int b = (unsigned)d / NPB;
            my_b[k] = b;
            my_p[k] = ((d - b * NPB) << 16) | src[e];
            my_w[k] = w[e];
            atomicAdd(&lh[b], 1);
        } else {
            my_b[k] = -1;
        }
    }
    __syncthreads();

    // exclusive scan of NB counts over all BT=512 threads
    const int v = (t < NB) ? lh[t] : 0;
    part[t] = v;
    __syncthreads();
    for (int off = 1; off < BT; off <<= 1) {
        int p = (t >= off) ? part[t - off] : 0;
        __syncthreads();
        part[t] += p;
        __syncthreads();
    }
    if (t < NB) { loff[t] = part[t] - v; lcur[t] = part[t] - v; }
    __syncthreads();

#pragma unroll
    for (int k = 0; k < EPT; ++k) {
        if (my_b[k] >= 0) {
            const int p = atomicAdd(&lcur[my_b[k]], 1);
            stage[p] = make_int2(my_p[k], __float_as_int(my_w[k]));
            sbk[p] = (ushort_t)my_b[k];
        }
    }
    __syncthreads();

    if (t < NB && lh[t] > 0)
        gpos[t] = t * CAP + atomicAdd(&cursor[t], lh[t]);
    __syncthreads();

    const int tot = min(N_EDGES - base, CHUNK_E);
    for (int s = t; s < tot; s += BT) {
        const int b = sbk[s];
        bedges[gpos[b] + (s - loff[b])] = stage[s];
    }
}

// ---------------- K2: fused bucket gather (LDS fp32 acc) + MFMA linear ----------
// Block = one bucket (98 dst nodes). Phase 1: 16 waves stream the bucket's
// records, 8-deep row loads + independent ds_add_f32 into acc[ld][dim].
// Phase 2: 16 waves run the 7x4 grid of 16x16x32 MFMA tile-jobs (h from
// global, neigh from LDS acc), per-row guard at bucket/graph edges.
__global__ __launch_bounds__(GT) void gather_linear_kernel(
    const ushort_t* __restrict__ hb, const int2* __restrict__ bedges,
    const int* __restrict__ cursor,
    const float* __restrict__ Ws, const float* __restrict__ bs,
    const float* __restrict__ Wn, const float* __restrict__ bn,
    float* __restrict__ out)
{
    __shared__ float acc[ACC_ROWS * D];   // 28.7 KB

    const int b    = blockIdx.x;
    const int t    = threadIdx.x;
    const int wave = t >> 6;
    const int lane = t & 63;

    for (int i = t; i < ACC_ROWS * D; i += GT) acc[i] = 0.f;
    __syncthreads();

    // ---- phase 1: accumulate this bucket's messages into LDS ----
    const int cnt = min(cursor[b], CAP);
    const int gb  = b * CAP;
    const int per = (cnt + (GT / 64) - 1) / (GT / 64);
    const int e0  = wave * per;
    const int e1  = min(e0 + per, cnt);

    int e = e0;
    for (; e + 8 <= e1; e += 8) {
        int2  r[8];
        float v[8];
#pragma unroll
        for (int k = 0; k < 8; ++k) r[k] = bedges[gb + e + k];
#pragma unroll
        for (int k = 0; k < 8; ++k)
            v[k] = b2f(hb[(size_t)(r[k].x & 0xFFFF) * D + lane]);
#pragma unroll
        for (int k = 0; k < 8; ++k)
            atomicAdd(&acc[(r[k].x >> 16) * D + lane],
                      __int_as_float(r[k].y) * v[k]);
    }
    for (; e < e1; ++e) {
        const int2 r = bedges[gb + e];
        atomicAdd(&acc[(r.x >> 16) * D + lane],
                  __int_as_float(r.y) * b2f(hb[(size_t)(r.x & 0xFFFF) * D + lane]));
    }
    __syncthreads();

    // ---- phase 2: MFMA linear over the bucket's nodes ----
    const int bstart   = b * NPB;
    const int nloc_end = min(NPB, N_NODES - bstart);   // nodes in this bucket
    const int ngroups  = (nloc_end + 15) >> 4;
    const int row16    = lane & 15;
    const int quad     = lane >> 4;

    for (int job = wave; job < ngroups * 4; job += GT / 64) {
        const int ng = job >> 2;
        const int ct = job & 3;
        const int n0 = bstart + ng * 16;

        // A-frags: h rows from global (clamped), neigh rows from LDS acc
        const int arow = min(n0 + row16, N_NODES - 1);
        const size_t abase = (size_t)arow * D + quad * 8;
        const short8 ah0 = *(const short8*)(hb + abase);
        const short8 ah1 = *(const short8*)(hb + abase + 32);
        const int nl = ng * 16 + row16;              // < ACC_ROWS (111 max)
        short8 an0, an1;
#pragma unroll
        for (int k = 0; k < 8; ++k)
            an0[k] = (short)f2b(acc[nl * D + quad * 8 + k]);
#pragma unroll
        for (int k = 0; k < 8; ++k)
            an1[k] = (short)f2b(acc[nl * D + 32 + quad * 8 + k]);

        const int col = ct * 16 + row16;
        const float* wsr = Ws + (size_t)col * D + quad * 8;
        const float* wnr = Wn + (size_t)col * D + quad * 8;
        short8 bw[4];   // ws_k0, ws_k1, wn_k0, wn_k1
#pragma unroll
        for (int f = 0; f < 4; ++f) {
            const float* p = (f < 2 ? wsr : wnr) + (f & 1) * 32;
            const float4 w0 = *(const float4*)p;
            const float4 w1 = *(const float4*)(p + 4);
            short8 bwv;
            bwv[0] = (short)f2b(w0.x); bwv[1] = (short)f2b(w0.y);
            bwv[2] = (short)f2b(w0.z); bwv[3] = (short)f2b(w0.w);
            bwv[4] = (short)f2b(w1.x); bwv[5] = (short)f2b(w1.y);
            bwv[6] = (short)f2b(w1.z); bwv[7] = (short)f2b(w1.w);
            bw[f] = bwv;
        }
        float4v c = {0.f, 0.f, 0.f, 0.f};
        c = __builtin_amdgcn_mfma_f32_16x16x32_bf16(ah0, bw[0], c, 0, 0, 0);
        c = __builtin_amdgcn_mfma_f32_16x16x32_bf16(ah1, bw[1], c, 0, 0, 0);
        c = __builtin_amdgcn_mfma_f32_16x16x32_bf16(an0, bw[2], c, 0, 0, 0);
        c = __builtin_amdgcn_mfma_f32_16x16x32_bf16(an1, bw[3], c, 0, 0, 0);

        const float bias = bs[col] + bn[col];
#pragma unroll
        for (int r = 0; r < 4; ++r) {
            const int nli = ng * 16 + quad * 4 + r;
            if (nli < nloc_end)
                out[(size_t)(bstart + nli) * D + col] = fmaxf(c[r] + bias, 0.f);
        }
    }
}

// ---------------- fallback path (ws too small): fp32 atomic scatter ----------------
__global__ __launch_bounds__(256) void sage_scatter(
    const float* __restrict__ h,
    const int* __restrict__ edge_src,
    const int* __restrict__ edge_dst,
    const float* __restrict__ edge_w,
    float* __restrict__ neigh)
{
    const long long tid = (long long)blockIdx.x * blockDim.x + threadIdx.x;
    const int e = (int)(tid >> 6);
    const int d = (int)(tid & 63);
    if (e >= N_EDGES) return;
    atomicAdd(&neigh[(long long)edge_dst[e] * D + d],
              edge_w[e] * h[(long long)edge_src[e] * D + d]);
}

__global__ __launch_bounds__(256, 2) void linear_f32_kernel(
    const float* __restrict__ h, const float* __restrict__ neigh,
    const float* __restrict__ Ws, const float* __restrict__ bs,
    const float* __restrict__ Wn, const float* __restrict__ bn,
    float* __restrict__ out)
{
    const int lane   = threadIdx.x & 63;
    const int gwave  = (blockIdx.x * blockDim.x + threadIdx.x) >> 6;
    const int nwaves = (gridDim.x * blockDim.x) >> 6;

    float Wsr[D], Wnr[D];
#pragma unroll
    for (int k = 0; k < D; k += 4) {
        const float4 a = *(const float4*)&Ws[(size_t)lane * D + k];
        const float4 b = *(const float4*)&Wn[(size_t)lane * D + k];
        Wsr[k] = a.x; Wsr[k+1] = a.y; Wsr[k+2] = a.z; Wsr[k+3] = a.w;
        Wnr[k] = b.x; Wnr[k+1] = b.y; Wnr[k+2] = b.z; Wnr[k+3] = b.w;
    }
    const float bias = bs[lane] + bn[lane];

    for (int n = gwave; n < N_NODES; n += nwaves) {
        const float hv = h[(size_t)n * D + lane];
        const float nv = neigh[(size_t)n * D + lane];
        float o = bias;
#pragma unroll
        for (int k = 0; k < D; ++k) {
            o = fmaf(lane_bcast(hv, k), Wsr[k], o);
            o = fmaf(lane_bcast(nv, k), Wnr[k], o);
        }
        out[(size_t)n * D + lane] = fmaxf(o, 0.f);
    }
}

extern "C" void kernel_launch(void* const* d_in, const int* in_sizes, int n_in,
                              void* d_out, int out_size, void* d_ws, size_t ws_size,
                              hipStream_t stream)
{
    const float* h        = (const float*)d_in[0];
    const int*   edge_src = (const int*)d_in[1];
    const int*   edge_dst = (const int*)d_in[2];
    const float* edge_w   = (const float*)d_in[3];
    const float* W_self   = (const float*)d_in[4];
    const float* b_self   = (const float*)d_in[5];
    const float* W_neigh  = (const float*)d_in[6];
    const float* b_neigh  = (const float*)d_in[7];
    float*       out      = (float*)d_out;

    // ws layout
    int2*     bedges = (int2*)d_ws;                               // NB*CAP int2
    ushort_t* hb     = (ushort_t*)(bedges + (size_t)NB * CAP);    // N*D ushort
    int*      cursor = (int*)(hb + (size_t)N_NODES * D);          // NB
    const size_t needed = (size_t)NB * CAP * 8 + (size_t)N_NODES * D * 2 + NB * 4;

    if (ws_size >= needed) {
        hipMemsetAsync(cursor, 0, NB * sizeof(int), stream);
        bin_h2b_kernel<<<NCHUNKS * 2, BT, 0, stream>>>(
            edge_src, edge_dst, edge_w, cursor, bedges, h, hb);
        gather_linear_kernel<<<NB, GT, 0, stream>>>(
            hb, bedges, cursor, W_self, b_self, W_neigh, b_neigh, out);
    } else {
        float* neigh_fb = (float*)d_ws;
        hipMemsetAsync(neigh_fb, 0, (size_t)N_NODES * D * sizeof(float), stream);
        const long long total = (long long)N_EDGES * 64;
        sage_scatter<<<(int)((total + 255) / 256), 256, 0, stream>>>(
            h, edge_src, edge_dst, edge_w, neigh_fb);
        linear_f32_kernel<<<1024, 256, 0, stream>>>(h, neigh_fb, W_self, b_self,
                                                    W_neigh, b_neigh, out);
    }
}

// Round 14
// 144.881 us; speedup vs baseline: 2.5931x; 2.5931x over previous
//
#include <hip/hip_runtime.h>

#define N_NODES 50000
#define N_EDGES 800000
#define D 64

#define NPB 200                      // nodes per bucket
#define NB  250                      // buckets (NPB*NB == N_NODES)
#define CAP 4096                     // record capacity per bucket (mean 3200, 15.8 sigma)
#define BT  512                      // threads for bin (8 waves)
#define EPT 4                        // edges per thread in bin
#define CHUNK_E (BT * EPT)           // 2048 edges per block
#define NCHUNKS ((N_EDGES + CHUNK_E - 1) / CHUNK_E)   // 391
#define CT  1024                     // bucket_csr threads (16 waves)
#define GBLK 16                      // nodes per fused gather+linear block (= 1 MFMA tile)

typedef unsigned short ushort_t;
typedef unsigned int   uint_t;
typedef __attribute__((ext_vector_type(8))) short   short8;
typedef __attribute__((ext_vector_type(4))) float   float4v;

// bf16 helpers (RNE down-convert; up-convert is exact)
__device__ __forceinline__ ushort_t f2b(float f) {
    uint_t u = __float_as_uint(f);
    return (ushort_t)((u + 0x7FFFu + ((u >> 16) & 1u)) >> 16);
}
__device__ __forceinline__ float b2f(ushort_t b) {
    return __uint_as_float((uint_t)b << 16);
}
// fp32 bits -> bf16 bits (RNE), kept in the HIGH 16 bits of a uint
__device__ __forceinline__ uint_t rne_hi16(uint_t u) {
    return (u + 0x7FFFu + ((u >> 16) & 1u)) & 0xFFFF0000u;
}
__device__ __forceinline__ float lane_bcast(float v, int l) {
    return __int_as_float(__builtin_amdgcn_readlane(__float_as_int(v), l));
}

// ---------------------------------------------------------------------------
// ws layout (16B-aligned sections):
//   bedges : int2[NB*CAP]     (8.19 MB) bucket-grouped packed records (bin out)
//   pedges : uint[NB*CAP]     (4.10 MB) node-sorted records: src | (w_bf16<<16)
//   offs2  : int2[N_NODES]    (0.4 MB)  per-node (beg,end) into pedges
//   h_bf16 : ushort[N*D]      (6.4 MB)
//   cursor : int[NB]          (memset 0; bin rebases to b*CAP + old)
// Binned record: .x=(src<<8)|local_dst, .y=bits(w).
// neigh never touches global: staged in LDS inside the fused kernel.
//
// Structure notes (evidence across R1-R13):
//  - sort-then-register-accumulate beats atomic accumulation 3-6x
//    (R4 global atomics, R13 LDS ds_add_f32 both lost).
//  - gather is pinned at ~47 us: random-row transaction floor
//    (invariant across record width, MLP depth, fusion shape).
//  - fused gather+MFMA at GBLK=16/512thr keeps 25k waves -> R9-level MLP.
// ---------------------------------------------------------------------------

// ---------------- K1: bin edges by bucket (blocks < NCHUNKS) + h->bf16 (rest) ----
__global__ __launch_bounds__(BT) void bin_h2b_kernel(
    const int* __restrict__ src, const int* __restrict__ dst,
    const float* __restrict__ w, int* __restrict__ cursor,
    int2* __restrict__ bedges,
    const float* __restrict__ h, ushort_t* __restrict__ hb)
{
    if (blockIdx.x >= NCHUNKS) {
        const int nb = gridDim.x - NCHUNKS;
        for (int i = (blockIdx.x - NCHUNKS) * BT + threadIdx.x;
             i < N_NODES * D / 4; i += nb * BT) {
            const float4 v = ((const float4*)h)[i];
            ushort4 o;
            o.x = f2b(v.x); o.y = f2b(v.y); o.z = f2b(v.z); o.w = f2b(v.w);
            ((ushort4*)hb)[i] = o;
        }
        return;
    }

    __shared__ int lh[NB];
    __shared__ int loff[NB];
    __shared__ int lcur[NB];
    __shared__ int gpos[NB];
    __shared__ int part[256];
    __shared__ int2 stage[CHUNK_E];
    __shared__ unsigned char sbk[CHUNK_E];

    const int t = threadIdx.x;
    for (int i = t; i < NB; i += BT) lh[i] = 0;
    __syncthreads();

    const int base = blockIdx.x * CHUNK_E;
    int   my_b[EPT];
    int   my_p[EPT];
    float my_w[EPT];
#pragma unroll
    for (int k = 0; k < EPT; ++k) {
        const int e = base + k * BT + t;
        if (e < N_EDGES) {
            const int d = dst[e];
            const int b = (unsigned)d / NPB;
            my_b[k] = b;
            my_p[k] = (src[e] << 8) | (d - b * NPB);
            my_w[k] = w[e];
            atomicAdd(&lh[b], 1);
        } else {
            my_b[k] = -1;
        }
    }
    __syncthreads();

    const int v = (t < NB) ? lh[t] : 0;
    if (t < 256) part[t] = v;
    __syncthreads();
    for (int off = 1; off < 256; off <<= 1) {
        int p = 0;
        if (t < 256 && t >= off) p = part[t - off];
        __syncthreads();
        if (t < 256) part[t] += p;
        __syncthreads();
    }
    if (t < NB) { loff[t] = part[t] - v; lcur[t] = part[t] - v; }
    __syncthreads();

#pragma unroll
    for (int k = 0; k < EPT; ++k) {
        if (my_b[k] >= 0) {
            const int p = atomicAdd(&lcur[my_b[k]], 1);
            stage[p] = make_int2(my_p[k], __float_as_int(my_w[k]));
            sbk[p] = (unsigned char)my_b[k];
        }
    }
    __syncthreads();

    if (t < NB && lh[t] > 0)
        gpos[t] = t * CAP + atomicAdd(&cursor[t], lh[t]);
    __syncthreads();

    const int tot = min(N_EDGES - base, CHUNK_E);
    for (int s = t; s < tot; s += BT) {
        const int b = sbk[s];
        bedges[gpos[b] + (s - loff[b])] = stage[s];
    }
}

// ---------------- K2: per-bucket node-exact CSR -> packed 4-B records ----------
__global__ __launch_bounds__(CT) void bucket_csr_kernel(
    const int* __restrict__ cursor, const int2* __restrict__ bedges,
    uint_t* __restrict__ pedges, int2* __restrict__ offs2)
{
    __shared__ int    lcur[NPB];
    __shared__ int    part[256];
    __shared__ uint_t stage[CAP];   // 16 KB

    const int b   = blockIdx.x;
    const int t   = threadIdx.x;
    const int gb  = b * CAP;
    const int cnt = min(cursor[b], CAP);

    // per-node histogram
    if (t < NPB) lcur[t] = 0;
    __syncthreads();
    for (int e = t; e < cnt; e += CT)
        atomicAdd(&lcur[bedges[gb + e].x & 255], 1);
    __syncthreads();

    // exclusive scan of NPB counts (first 256 threads)
    const int v = (t < NPB) ? lcur[t] : 0;
    if (t < 256) part[t] = v;
    __syncthreads();
    for (int off = 1; off < 256; off <<= 1) {
        int p = 0;
        if (t < 256 && t >= off) p = part[t - off];
        __syncthreads();
        if (t < 256) part[t] += p;
        __syncthreads();
    }
    if (t < NPB) {
        const int ex = part[t] - v;
        lcur[t] = ex;
        offs2[b * NPB + t] = make_int2(gb + ex, gb + ex + v);
    }
    __syncthreads();

    // position via LDS atomics, scatter PACKED into LDS stage
    for (int e = t; e < cnt; e += CT) {
        const int2 r = bedges[gb + e];
        const int p = atomicAdd(&lcur[r.x & 255], 1);
        stage[p] = (uint_t)(r.x >> 8) | rne_hi16((uint_t)r.y);
    }
    __syncthreads();
    // fully coalesced flush to pedges
    for (int s = t; s < cnt; s += CT)
        pedges[gb + s] = stage[s];
}

// ---------------- K3: fused gather (8 waves x 2 nodes, 16-deep) + MFMA linear ----
__global__ __launch_bounds__(512) void gather_linear_kernel(
    const ushort_t* __restrict__ hb, const uint_t* __restrict__ pedges,
    const int2* __restrict__ offs2,
    const float* __restrict__ Ws, const float* __restrict__ bs,
    const float* __restrict__ Wn, const float* __restrict__ bn,
    float* __restrict__ out)
{
    __shared__ ushort_t nstage[GBLK * D];   // 2 KB

    const int wave  = threadIdx.x >> 6;     // 0..7
    const int lane  = threadIdx.x & 63;
    const int node0 = blockIdx.x * GBLK;

    // ---- phase 1: 2 nodes per wave, 16-deep MLP ----
#pragma unroll
    for (int jj = 0; jj < 2; ++jj) {
        const int j = wave * 2 + jj;        // node-in-block 0..15
        const int node = node0 + j;
        if (node < N_NODES) {
            const int2 be = offs2[node];
            const int beg = be.x, end = be.y;
            float acc = 0.f;
            int e = beg;
            for (; e + 16 <= end; e += 16) {
                uint_t r[16];
                float  vv[16];
#pragma unroll
                for (int k = 0; k < 16; ++k) r[k] = pedges[e + k];
#pragma unroll
                for (int k = 0; k < 16; ++k)
                    vv[k] = b2f(hb[(size_t)(r[k] & 0xFFFFu) * D + lane]);
#pragma unroll
                for (int k = 0; k < 16; ++k)
                    acc = fmaf(__uint_as_float(r[k] & 0xFFFF0000u), vv[k], acc);
            }
            for (; e + 4 <= end; e += 4) {
                uint_t r[4];
                float  vv[4];
#pragma unroll
                for (int k = 0; k < 4; ++k) r[k] = pedges[e + k];
#pragma unroll
                for (int k = 0; k < 4; ++k)
                    vv[k] = b2f(hb[(size_t)(r[k] & 0xFFFFu) * D + lane]);
#pragma unroll
                for (int k = 0; k < 4; ++k)
                    acc = fmaf(__uint_as_float(r[k] & 0xFFFF0000u), vv[k], acc);
            }
            for (; e < end; ++e) {
                const uint_t r = pedges[e];
                acc = fmaf(__uint_as_float(r & 0xFFFF0000u),
                           b2f(hb[(size_t)(r & 0xFFFFu) * D + lane]), acc);
            }
            nstage[j * D + lane] = f2b(acc);
        }
    }
    __syncthreads();

    // ---- phase 2: waves 0-3, one 16-col tile each ----
    const int nt = wave;
    if (nt >= 4 || node0 >= N_NODES) return;
    const int row16 = lane & 15;
    const int quad  = lane >> 4;

    const size_t abase = (size_t)(node0 + row16) * D + quad * 8;
    const short8 ah0 = *(const short8*)(hb + abase);
    const short8 ah1 = *(const short8*)(hb + abase + 32);
    const ushort_t* sp = nstage + row16 * D + quad * 8;
    const short8 an0 = *(const short8*)sp;
    const short8 an1 = *(const short8*)(sp + 32);

    const int col = nt * 16 + row16;
    const float* wsr = Ws + (size_t)col * D + quad * 8;
    const float* wnr = Wn + (size_t)col * D + quad * 8;
    short8 bw[4];   // ws_k0, ws_k1, wn_k0, wn_k1
#pragma unroll
    for (int f = 0; f < 4; ++f) {
        const float* p = (f < 2 ? wsr : wnr) + (f & 1) * 32;
        const float4 w0 = *(const float4*)p;
        const float4 w1 = *(const float4*)(p + 4);
        short8 bwv;
        bwv[0] = (short)f2b(w0.x); bwv[1] = (short)f2b(w0.y);
        bwv[2] = (short)f2b(w0.z); bwv[3] = (short)f2b(w0.w);
        bwv[4] = (short)f2b(w1.x); bwv[5] = (short)f2b(w1.y);
        bwv[6] = (short)f2b(w1.z); bwv[7] = (short)f2b(w1.w);
        bw[f] = bwv;
    }
    float4v acc = {0.f, 0.f, 0.f, 0.f};
    acc = __builtin_amdgcn_mfma_f32_16x16x32_bf16(ah0, bw[0], acc, 0, 0, 0);
    acc = __builtin_amdgcn_mfma_f32_16x16x32_bf16(ah1, bw[1], acc, 0, 0, 0);
    acc = __builtin_amdgcn_mfma_f32_16x16x32_bf16(an0, bw[2], acc, 0, 0, 0);
    acc = __builtin_amdgcn_mfma_f32_16x16x32_bf16(an1, bw[3], acc, 0, 0, 0);

    const float bias = bs[col] + bn[col];
#pragma unroll
    for (int r = 0; r < 4; ++r) {
        const int m = quad * 4 + r;
        out[(size_t)(node0 + m) * D + col] = fmaxf(acc[r] + bias, 0.f);
    }
}

// ---------------- fallback path (ws too small): fp32 atomic scatter ----------------
__global__ __launch_bounds__(256) void sage_scatter(
    const float* __restrict__ h,
    const int* __restrict__ edge_src,
    const int* __restrict__ edge_dst,
    const float* __restrict__ edge_w,
    float* __restrict__ neigh)
{
    const long long tid = (long long)blockIdx.x * blockDim.x + threadIdx.x;
    const int e = (int)(tid >> 6);
    const int d = (int)(tid & 63);
    if (e >= N_EDGES) return;
    atomicAdd(&neigh[(long long)edge_dst[e] * D + d],
              edge_w[e] * h[(long long)edge_src[e] * D + d]);
}

__global__ __launch_bounds__(256, 2) void linear_f32_kernel(
    const float* __restrict__ h, const float* __restrict__ neigh,
    const float* __restrict__ Ws, const float* __restrict__ bs,
    const float* __restrict__ Wn, const float* __restrict__ bn,
    float* __restrict__ out)
{
    const int lane   = threadIdx.x & 63;
    const int gwave  = (blockIdx.x * blockDim.x + threadIdx.x) >> 6;
    const int nwaves = (gridDim.x * blockDim.x) >> 6;

    float Wsr[D], Wnr[D];
#pragma unroll
    for (int k = 0; k < D; k += 4) {
        const float4 a = *(const float4*)&Ws[(size_t)lane * D + k];
        const float4 b = *(const float4*)&Wn[(size_t)lane * D + k];
        Wsr[k] = a.x; Wsr[k+1] = a.y; Wsr[k+2] = a.z; Wsr[k+3] = a.w;
        Wnr[k] = b.x; Wnr[k+1] = b.y; Wnr[k+2] = b.z; Wnr[k+3] = b.w;
    }
    const float bias = bs[lane] + bn[lane];

    for (int n = gwave; n < N_NODES; n += nwaves) {
        const float hv = h[(size_t)n * D + lane];
        const float nv = neigh[(size_t)n * D + lane];
        float o = bias;
#pragma unroll
        for (int k = 0; k < D; ++k) {
            o = fmaf(lane_bcast(hv, k), Wsr[k], o);
            o = fmaf(lane_bcast(nv, k), Wnr[k], o);
        }
        out[(size_t)n * D + lane] = fmaxf(o, 0.f);
    }
}

extern "C" void kernel_launch(void* const* d_in, const int* in_sizes, int n_in,
                              void* d_out, int out_size, void* d_ws, size_t ws_size,
                              hipStream_t stream)
{
    const float* h        = (const float*)d_in[0];
    const int*   edge_src = (const int*)d_in[1];
    const int*   edge_dst = (const int*)d_in[2];
    const float* edge_w   = (const float*)d_in[3];
    const float* W_self   = (const float*)d_in[4];
    const float* b_self   = (const float*)d_in[5];
    const float* W_neigh  = (const float*)d_in[6];
    const float* b_neigh  = (const float*)d_in[7];
    float*       out      = (float*)d_out;

    // ws layout
    int2*     bedges = (int2*)d_ws;                               // NB*CAP int2
    uint_t*   pedges = (uint_t*)(bedges + (size_t)NB * CAP);      // NB*CAP uint
    int2*     offs2  = (int2*)(pedges + (size_t)NB * CAP);        // N_NODES int2
    ushort_t* hb     = (ushort_t*)(offs2 + N_NODES);              // N*D ushort
    int*      cursor = (int*)(hb + (size_t)N_NODES * D);          // NB
    const size_t needed = (size_t)NB * CAP * 8 + (size_t)NB * CAP * 4
                        + (size_t)N_NODES * 8 + (size_t)N_NODES * D * 2 + NB * 4;

    if (ws_size >= needed) {
        hipMemsetAsync(cursor, 0, NB * sizeof(int), stream);
        bin_h2b_kernel<<<NCHUNKS * 2, BT, 0, stream>>>(
            edge_src, edge_dst, edge_w, cursor, bedges, h, hb);
        bucket_csr_kernel<<<NB, CT, 0, stream>>>(cursor, bedges, pedges, offs2);
        gather_linear_kernel<<<(N_NODES + GBLK - 1) / GBLK, 512, 0, stream>>>(
            hb, pedges, offs2, W_self, b_self, W_neigh, b_neigh, out);
    } else {
        float* neigh_fb = (float*)d_ws;
        hipMemsetAsync(neigh_fb, 0, (size_t)N_NODES * D * sizeof(float), stream);
        const long long total = (long long)N_EDGES * 64;
        sage_scatter<<<(int)((total + 255) / 256), 256, 0, stream>>>(
            h, edge_src, edge_dst, edge_w, neigh_fb);
        linear_f32_kernel<<<1024, 256, 0, stream>>>(h, neigh_fb, W_self, b_self,
                                                    W_neigh, b_neigh, out);
    }
}